// Round 1
// baseline (381.043 us; speedup 1.0000x reference)
//
#include <hip/hip_runtime.h>

// ---------------------------------------------------------------------------
// FlaxAttention: x@Wqkv -> LN(q),LN(k) -> causal flash attn -> ctx@out_W
// B=2 S=2048 D=2048 H=16 Dh=128. All matmuls bf16 MFMA (fp32 accum).
// ---------------------------------------------------------------------------

typedef float f32x4 __attribute__((ext_vector_type(4)));
typedef short s16x8 __attribute__((ext_vector_type(8)));
typedef short s16x4 __attribute__((ext_vector_type(4)));

static __device__ __forceinline__ unsigned short f2bf(float f) {
  unsigned u = __builtin_bit_cast(unsigned, f);
  unsigned r = u + 0x7fffu + ((u >> 16) & 1u);   // RNE
  return (unsigned short)(r >> 16);
}
static __device__ __forceinline__ float bf2f(unsigned short s) {
  unsigned u = ((unsigned)s) << 16;
  return __builtin_bit_cast(float, u);
}

static __device__ __forceinline__ void gload_lds16(const unsigned short* g, unsigned short* l) {
  __builtin_amdgcn_global_load_lds((const __attribute__((address_space(1))) void*)g,
                                   (__attribute__((address_space(3))) void*)l, 16, 0, 0);
}

// --------------------------- fp32 -> bf16 convert ---------------------------
__global__ __launch_bounds__(256) void k_cvt4(const float4* __restrict__ in,
                                              s16x4* __restrict__ out, int n) {
  int i = blockIdx.x * 256 + threadIdx.x;
  if (i >= n) return;
  float4 v = in[i];
  s16x4 o = { (short)f2bf(v.x), (short)f2bf(v.y), (short)f2bf(v.z), (short)f2bf(v.w) };
  out[i] = o;
}

// ------------------- W [K][N] f32 -> W^T [N][K] bf16 ------------------------
__global__ __launch_bounds__(256) void k_twT(const float* __restrict__ in,
                                             unsigned short* __restrict__ out,
                                             int K, int N) {
  __shared__ float tile[32][33];
  const int n0 = blockIdx.x * 32, k0 = blockIdx.y * 32;
  const int tx = threadIdx.x & 31, ty = threadIdx.x >> 5;
#pragma unroll
  for (int rr = 0; rr < 4; ++rr) {
    int kr = ty + rr * 8;
    tile[kr][tx] = in[(size_t)(k0 + kr) * N + n0 + tx];
  }
  __syncthreads();
#pragma unroll
  for (int rr = 0; rr < 4; ++rr) {
    int nr = ty + rr * 8;
    out[(size_t)(n0 + nr) * K + k0 + tx] = f2bf(tile[tx][nr]);
  }
}

// --------------- GEMM C[M][N] = A[M][K] * Bt[N][K]^T (bf16 MFMA) ------------
// 128x128 tile, BK=32, 4 waves (2x2), each wave 64x64 via 4x4 16x16x32 frags.
template <int BF16OUT>
__global__ __launch_bounds__(256) void k_gemm(const unsigned short* __restrict__ A,
                                              const unsigned short* __restrict__ Bt,
                                              void* __restrict__ Cout,
                                              int M, int N, int K) {
  __shared__ unsigned short sA[128 * 32];
  __shared__ unsigned short sB[128 * 32];
  const int t = threadIdx.x;
  const int w = t >> 6, lane = t & 63, g = lane >> 4, l15 = lane & 15;
  const int m0 = blockIdx.y * 128, n0 = blockIdx.x * 128;
  const int wm = (w >> 1) * 64, wn = (w & 1) * 64;
  f32x4 acc[4][4];
#pragma unroll
  for (int i = 0; i < 4; i++)
#pragma unroll
    for (int j = 0; j < 4; j++) acc[i][j] = (f32x4){0.f, 0.f, 0.f, 0.f};

  const int nk = K >> 5;
  for (int kt = 0; kt < nk; ++kt) {
    __syncthreads();
#pragma unroll
    for (int it = 0; it < 2; ++it) {
      int flat = it * 256 + t;
      int row = flat >> 2, ch = flat & 3;
      gload_lds16(A  + (size_t)(m0 + row) * K + kt * 32 + ch * 8,
                  sA + (size_t)(it * 256 + w * 64) * 8);
      gload_lds16(Bt + (size_t)(n0 + row) * K + kt * 32 + ch * 8,
                  sB + (size_t)(it * 256 + w * 64) * 8);
    }
    __syncthreads();
    s16x8 af[4], bf[4];
#pragma unroll
    for (int i = 0; i < 4; i++) {
      af[i] = *(const s16x8*)&sA[(wm + i * 16 + l15) * 32 + 8 * g];
      bf[i] = *(const s16x8*)&sB[(wn + i * 16 + l15) * 32 + 8 * g];
    }
#pragma unroll
    for (int i = 0; i < 4; i++)
#pragma unroll
      for (int j = 0; j < 4; j++)
        acc[i][j] = __builtin_amdgcn_mfma_f32_16x16x32_bf16(af[i], bf[j], acc[i][j], 0, 0, 0);
  }
#pragma unroll
  for (int i = 0; i < 4; i++) {
#pragma unroll
    for (int j = 0; j < 4; j++) {
#pragma unroll
      for (int r = 0; r < 4; r++) {
        int row = m0 + wm + i * 16 + 4 * g + r;
        int col = n0 + wn + j * 16 + l15;
        if (BF16OUT)
          ((unsigned short*)Cout)[(size_t)row * N + col] = f2bf(acc[i][j][r]);
        else
          ((float*)Cout)[(size_t)row * N + col] = acc[i][j][r];
      }
    }
  }
}

// ----------------- in-place LayerNorm on q,k parts of qkv -------------------
// q gets *= q_scale * (1/sqrt(128))*log2(e) so attn uses exp2 directly.
__global__ __launch_bounds__(256) void k_ln(unsigned short* __restrict__ qkv,
                                            const float* __restrict__ qsc,
                                            const float* __restrict__ ksc) {
  __shared__ float red[8];
  const int t = threadIdx.x;
  const int w = t >> 6;
  unsigned short* base = qkv + (size_t)blockIdx.x * 6144;
#pragma unroll
  for (int part = 0; part < 2; ++part) {
    unsigned short* p = base + part * 2048 + t * 8;
    s16x8 v = *(const s16x8*)p;
    float f[8], s = 0.f, q = 0.f;
#pragma unroll
    for (int j = 0; j < 8; j++) { f[j] = bf2f((unsigned short)v[j]); s += f[j]; q += f[j] * f[j]; }
#pragma unroll
    for (int m = 1; m < 64; m <<= 1) { s += __shfl_xor(s, m); q += __shfl_xor(q, m); }
    __syncthreads();
    if ((t & 63) == 0) { red[w] = s; red[4 + w] = q; }
    __syncthreads();
    s = red[0] + red[1] + red[2] + red[3];
    q = red[4] + red[5] + red[6] + red[7];
    float mean = s * (1.f / 2048.f);
    float var = q * (1.f / 2048.f) - mean * mean;
    float inv = rsqrtf(var + 1e-6f);
    const float* sc = part ? ksc : qsc;
    float extra = part ? 1.0f : 0.12751743f;  // (1/sqrt(128))*log2(e)
    s16x8 o;
#pragma unroll
    for (int j = 0; j < 8; j++) o[j] = (short)f2bf((f[j] - mean) * inv * (sc[t * 8 + j] * extra));
    *(s16x8*)p = o;
  }
}

// ------------- v part of qkv (bf16) -> v_t [b][h][d][s] bf16 ----------------
__global__ __launch_bounds__(256) void k_vT(const unsigned short* __restrict__ qkv,
                                            unsigned short* __restrict__ vt) {
  __shared__ unsigned short tl[64][136];
  const int bh = blockIdx.y;
  const int b = bh >> 4, h = bh & 15;
  const int s0 = blockIdx.x * 64;
  const int t = threadIdx.x;
#pragma unroll
  for (int it = 0; it < 4; ++it) {
    int flat = it * 256 + t;
    int r = flat >> 4, c = flat & 15;
    s16x8 v = *(const s16x8*)(qkv + (size_t)(b * 2048 + s0 + r) * 6144 + 4096 + h * 128 + c * 8);
    *((s16x8*)&tl[r][c * 8]) = v;
  }
  __syncthreads();
#pragma unroll
  for (int it = 0; it < 4; ++it) {
    int flat = it * 256 + t;
    int d = flat >> 3, cs = flat & 7;
    s16x8 o;
#pragma unroll
    for (int e = 0; e < 8; e++) o[e] = (short)tl[cs * 8 + e][d];
    *(s16x8*)(vt + (size_t)(bh * 128 + d) * 2048 + s0 + cs * 8) = o;
  }
}

// --------------------------- causal flash attention -------------------------
// 4 waves x 16 q rows = 64-row Q tile; KV tiles of 64. Swapped QK^T
// (mfma(K,Q)) so each lane owns full score rows for one q; P feeds PV's
// A-operand directly from C-layout regs. LDS XOR-swizzled (16B chunks),
// sources pre-swizzled for linear global_load_lds dest.
__global__ __launch_bounds__(256) void k_attn(const unsigned short* __restrict__ qkv,
                                              const unsigned short* __restrict__ vt,
                                              unsigned short* __restrict__ ctx) {
  __shared__ unsigned short sQ[64 * 128];
  __shared__ unsigned short sK[64 * 128];
  __shared__ unsigned short sV[128 * 64];
  const int t = threadIdx.x;
  const int w = t >> 6, lane = t & 63, g = lane >> 4, l15 = lane & 15;
  const int qt = (int)gridDim.x - 1 - (int)blockIdx.x;  // big tiles first
  const int h = blockIdx.y, b = blockIdx.z;
  const int q0 = qt * 64;
  const unsigned short* vbase = vt + (size_t)((b * 16 + h) * 128) * 2048;

#pragma unroll
  for (int it = 0; it < 4; ++it) {  // stage Q once (swizzled source)
    int flat = it * 256 + t;
    int r = flat >> 4, c = flat & 15;
    int cs = c ^ (r & 15);
    gload_lds16(qkv + (size_t)(b * 2048 + q0 + r) * 6144 + h * 128 + cs * 8,
                sQ + (size_t)(it * 256 + w * 64) * 8);
  }

  f32x4 o[8];
#pragma unroll
  for (int nd = 0; nd < 8; ++nd) o[nd] = (f32x4){0.f, 0.f, 0.f, 0.f};
  float mrun = -INFINITY, lrun = 0.f;

  const int ntiles = qt + 1;
  for (int kt = 0; kt < ntiles; ++kt) {
    const int k0 = kt * 64;
    __syncthreads();  // prev compute done; (iter0: Q loads drained)
#pragma unroll
    for (int it = 0; it < 4; ++it) {  // stage K
      int flat = it * 256 + t;
      int r = flat >> 4, c = flat & 15;
      int cs = c ^ (r & 15);
      gload_lds16(qkv + (size_t)(b * 2048 + k0 + r) * 6144 + 2048 + h * 128 + cs * 8,
                  sK + (size_t)(it * 256 + w * 64) * 8);
    }
#pragma unroll
    for (int it = 0; it < 4; ++it) {  // stage V^T
      int flat = it * 256 + t;
      int d = flat >> 3, c = flat & 7;
      int cs = c ^ (d & 7);
      gload_lds16(vbase + (size_t)d * 2048 + k0 + cs * 8,
                  sV + (size_t)(it * 256 + w * 64) * 8);
    }
    __syncthreads();

    s16x8 bq[4];
#pragma unroll
    for (int ks = 0; ks < 4; ++ks)
      bq[ks] = *(const s16x8*)&sQ[(w * 16 + l15) * 128 + (((ks * 4 + g) ^ l15) * 8)];

    f32x4 st[4];
#pragma unroll
    for (int mi = 0; mi < 4; ++mi) st[mi] = (f32x4){0.f, 0.f, 0.f, 0.f};
#pragma unroll
    for (int mi = 0; mi < 4; ++mi) {
#pragma unroll
      for (int ks = 0; ks < 4; ++ks) {
        s16x8 ak = *(const s16x8*)&sK[(mi * 16 + l15) * 128 + (((ks * 4 + g) ^ l15) * 8)];
        st[mi] = __builtin_amdgcn_mfma_f32_16x16x32_bf16(ak, bq[ks], st[mi], 0, 0, 0);
      }
    }
    // st[mi][r] = S^T[key = mi*16+4g+r][q = w*16+l15] (pre-scaled, log2 domain)

    if (kt == ntiles - 1) {  // diagonal tile: causal mask
      const int qloc = w * 16 + l15;
#pragma unroll
      for (int mi = 0; mi < 4; ++mi)
#pragma unroll
        for (int r = 0; r < 4; ++r)
          if (mi * 16 + 4 * g + r > qloc) st[mi][r] = -INFINITY;
    }

    float mt = -INFINITY;
#pragma unroll
    for (int mi = 0; mi < 4; ++mi)
#pragma unroll
      for (int r = 0; r < 4; ++r) mt = fmaxf(mt, st[mi][r]);
    mt = fmaxf(mt, __shfl_xor(mt, 16));
    mt = fmaxf(mt, __shfl_xor(mt, 32));
    const float mnew = fmaxf(mrun, mt);
    const float alpha = exp2f(mrun - mnew);
    float ls = 0.f;
#pragma unroll
    for (int mi = 0; mi < 4; ++mi)
#pragma unroll
      for (int r = 0; r < 4; ++r) {
        float pp = exp2f(st[mi][r] - mnew);
        st[mi][r] = pp;
        ls += pp;
      }
    ls += __shfl_xor(ls, 16);
    ls += __shfl_xor(ls, 32);
    lrun = alpha * lrun + ls;
    mrun = mnew;

    float ar[4];
#pragma unroll
    for (int r = 0; r < 4; ++r) ar[r] = __shfl(alpha, 4 * g + r);
#pragma unroll
    for (int nd = 0; nd < 8; ++nd)
#pragma unroll
      for (int r = 0; r < 4; ++r) o[nd][r] *= ar[r];

    s16x8 pa01, pa23;  // P as PV A-operand: slot j <-> key (j&3)+4g+16*(j>>2)
#pragma unroll
    for (int j = 0; j < 8; ++j) {
      pa01[j] = (short)f2bf(st[j >> 2][j & 3]);
      pa23[j] = (short)f2bf(st[2 + (j >> 2)][j & 3]);
    }

#pragma unroll
    for (int nd = 0; nd < 8; ++nd) {
      const int d = nd * 16 + l15;
#pragma unroll
      for (int ch = 0; ch < 2; ++ch) {
        const int cb = (g >> 1) + 4 * ch;
        s16x4 lo = *(const s16x4*)&sV[d * 64 + (((cb)     ^ (d & 7)) * 8) + (g & 1) * 4];
        s16x4 hi = *(const s16x4*)&sV[d * 64 + (((cb + 2) ^ (d & 7)) * 8) + (g & 1) * 4];
        s16x8 bv = __builtin_shufflevector(lo, hi, 0, 1, 2, 3, 4, 5, 6, 7);
        o[nd] = __builtin_amdgcn_mfma_f32_16x16x32_bf16(ch ? pa23 : pa01, bv, o[nd], 0, 0, 0);
      }
    }
  }

  float ivr[4];
#pragma unroll
  for (int r = 0; r < 4; ++r) {
    float lv = __shfl(lrun, 4 * g + r);
    ivr[r] = 1.0f / lv;
  }
#pragma unroll
  for (int nd = 0; nd < 8; ++nd) {
    const int col = h * 128 + nd * 16 + l15;
#pragma unroll
    for (int r = 0; r < 4; ++r) {
      const int row = b * 2048 + q0 + w * 16 + 4 * g + r;
      ctx[(size_t)row * 2048 + col] = f2bf(o[nd][r] * ivr[r]);
    }
  }
}

// ---------------------------------------------------------------------------
extern "C" void kernel_launch(void* const* d_in, const int* in_sizes, int n_in,
                              void* d_out, int out_size, void* d_ws, size_t ws_size,
                              hipStream_t stream) {
  (void)in_sizes; (void)n_in; (void)out_size; (void)ws_size;
  const float* x    = (const float*)d_in[0];
  const float* Wqkv = (const float*)d_in[1];
  const float* qsc  = (const float*)d_in[2];
  const float* ksc  = (const float*)d_in[3];
  const float* outW = (const float*)d_in[4];

  char* ws = (char*)d_ws;
  unsigned short* xb  = (unsigned short*)(ws);              // 16.8MB (reused as ctx)
  unsigned short* wT  = (unsigned short*)(ws + 16777216);   // 25.2MB  Wqkv^T bf16
  unsigned short* owT = (unsigned short*)(ws + 41943040);   // 8.4MB   out_W^T bf16
  unsigned short* qkv = (unsigned short*)(ws + 50331648);   // 50.3MB  qkv bf16 (LN in place)
  unsigned short* vt  = (unsigned short*)(ws + 100663296);  // 16.8MB  v^T per head
  unsigned short* ctx = xb;                                 // x dead after QKV GEMM

  k_cvt4<<<8192, 256, 0, stream>>>((const float4*)x, (s16x4*)xb, 2097152);
  k_twT<<<dim3(192, 64), 256, 0, stream>>>(Wqkv, wT, 2048, 6144);
  k_twT<<<dim3(64, 64), 256, 0, stream>>>(outW, owT, 2048, 2048);
  k_gemm<1><<<dim3(48, 32), 256, 0, stream>>>(xb, wT, (void*)qkv, 4096, 6144, 2048);
  k_ln<<<4096, 256, 0, stream>>>(qkv, qsc, ksc);
  k_vT<<<dim3(32, 32), 256, 0, stream>>>(qkv, vt);
  k_attn<<<dim3(32, 16, 2), 256, 0, stream>>>(qkv, vt, ctx);
  k_gemm<0><<<dim3(16, 32), 256, 0, stream>>>(ctx, owT, d_out, 4096, 2048, 2048);
}

// Round 2
// 317.242 us; speedup vs baseline: 1.2011x; 1.2011x over previous
//
#include <hip/hip_runtime.h>

// ---------------------------------------------------------------------------
// FlaxAttention: x@Wqkv -> LN(q),LN(k) -> causal flash attn -> ctx@out_W
// B=2 S=2048 D=2048 H=16 Dh=128. All matmuls bf16 MFMA (fp32 accum).
// ---------------------------------------------------------------------------

typedef float f32x4 __attribute__((ext_vector_type(4)));
typedef short s16x8 __attribute__((ext_vector_type(8)));
typedef short s16x4 __attribute__((ext_vector_type(4)));

static __device__ __forceinline__ unsigned short f2bf(float f) {
  unsigned u = __builtin_bit_cast(unsigned, f);
  unsigned r = u + 0x7fffu + ((u >> 16) & 1u);   // RNE
  return (unsigned short)(r >> 16);
}
static __device__ __forceinline__ float bf2f(unsigned short s) {
  unsigned u = ((unsigned)s) << 16;
  return __builtin_bit_cast(float, u);
}

static __device__ __forceinline__ void gload_lds16(const unsigned short* g, unsigned short* l) {
  __builtin_amdgcn_global_load_lds((const __attribute__((address_space(1))) void*)g,
                                   (__attribute__((address_space(3))) void*)l, 16, 0, 0);
}

// --------------------------- fp32 -> bf16 convert ---------------------------
__global__ __launch_bounds__(256) void k_cvt4(const float4* __restrict__ in,
                                              s16x4* __restrict__ out, int n) {
  int i = blockIdx.x * 256 + threadIdx.x;
  if (i >= n) return;
  float4 v = in[i];
  s16x4 o = { (short)f2bf(v.x), (short)f2bf(v.y), (short)f2bf(v.z), (short)f2bf(v.w) };
  out[i] = o;
}

// ------------------- W [K][N] f32 -> W^T [N][K] bf16 ------------------------
__global__ __launch_bounds__(256) void k_twT(const float* __restrict__ in,
                                             unsigned short* __restrict__ out,
                                             int K, int N) {
  __shared__ float tile[32][33];
  const int n0 = blockIdx.x * 32, k0 = blockIdx.y * 32;
  const int tx = threadIdx.x & 31, ty = threadIdx.x >> 5;
#pragma unroll
  for (int rr = 0; rr < 4; ++rr) {
    int kr = ty + rr * 8;
    tile[kr][tx] = in[(size_t)(k0 + kr) * N + n0 + tx];
  }
  __syncthreads();
#pragma unroll
  for (int rr = 0; rr < 4; ++rr) {
    int nr = ty + rr * 8;
    out[(size_t)(n0 + nr) * K + k0 + tx] = f2bf(tile[tx][nr]);
  }
}

// --------------- GEMM C[M][N] = A[M][K] * Bt[N][K]^T (bf16 MFMA) ------------
// 128x128 tile, BK=32, 4 waves (2x2), each wave 64x64 via 4x4 16x16x32 frags.
template <int BF16OUT>
__global__ __launch_bounds__(256) void k_gemm(const unsigned short* __restrict__ A,
                                              const unsigned short* __restrict__ Bt,
                                              void* __restrict__ Cout,
                                              int M, int N, int K) {
  __shared__ unsigned short sA[128 * 32];
  __shared__ unsigned short sB[128 * 32];
  const int t = threadIdx.x;
  const int w = t >> 6, lane = t & 63, g = lane >> 4, l15 = lane & 15;
  const int m0 = blockIdx.y * 128, n0 = blockIdx.x * 128;
  const int wm = (w >> 1) * 64, wn = (w & 1) * 64;
  f32x4 acc[4][4];
#pragma unroll
  for (int i = 0; i < 4; i++)
#pragma unroll
    for (int j = 0; j < 4; j++) acc[i][j] = (f32x4){0.f, 0.f, 0.f, 0.f};

  const int nk = K >> 5;
  for (int kt = 0; kt < nk; ++kt) {
    __syncthreads();
#pragma unroll
    for (int it = 0; it < 2; ++it) {
      int flat = it * 256 + t;
      int row = flat >> 2, ch = flat & 3;
      gload_lds16(A  + (size_t)(m0 + row) * K + kt * 32 + ch * 8,
                  sA + (size_t)(it * 256 + w * 64) * 8);
      gload_lds16(Bt + (size_t)(n0 + row) * K + kt * 32 + ch * 8,
                  sB + (size_t)(it * 256 + w * 64) * 8);
    }
    __syncthreads();
    s16x8 af[4], bf[4];
#pragma unroll
    for (int i = 0; i < 4; i++) {
      af[i] = *(const s16x8*)&sA[(wm + i * 16 + l15) * 32 + 8 * g];
      bf[i] = *(const s16x8*)&sB[(wn + i * 16 + l15) * 32 + 8 * g];
    }
#pragma unroll
    for (int i = 0; i < 4; i++)
#pragma unroll
      for (int j = 0; j < 4; j++)
        acc[i][j] = __builtin_amdgcn_mfma_f32_16x16x32_bf16(af[i], bf[j], acc[i][j], 0, 0, 0);
  }
#pragma unroll
  for (int i = 0; i < 4; i++) {
#pragma unroll
    for (int j = 0; j < 4; j++) {
#pragma unroll
      for (int r = 0; r < 4; r++) {
        int row = m0 + wm + i * 16 + 4 * g + r;
        int col = n0 + wn + j * 16 + l15;
        if (BF16OUT)
          ((unsigned short*)Cout)[(size_t)row * N + col] = f2bf(acc[i][j][r]);
        else
          ((float*)Cout)[(size_t)row * N + col] = acc[i][j][r];
      }
    }
  }
}

// ----------------- in-place LayerNorm on q,k parts of qkv -------------------
// q gets *= q_scale * (1/sqrt(128))*log2(e) so attn uses exp2 directly.
__global__ __launch_bounds__(256) void k_ln(unsigned short* __restrict__ qkv,
                                            const float* __restrict__ qsc,
                                            const float* __restrict__ ksc) {
  __shared__ float red[8];
  const int t = threadIdx.x;
  const int w = t >> 6;
  unsigned short* base = qkv + (size_t)blockIdx.x * 6144;
#pragma unroll
  for (int part = 0; part < 2; ++part) {
    unsigned short* p = base + part * 2048 + t * 8;
    s16x8 v = *(const s16x8*)p;
    float f[8], s = 0.f, q = 0.f;
#pragma unroll
    for (int j = 0; j < 8; j++) { f[j] = bf2f((unsigned short)v[j]); s += f[j]; q += f[j] * f[j]; }
#pragma unroll
    for (int m = 1; m < 64; m <<= 1) { s += __shfl_xor(s, m); q += __shfl_xor(q, m); }
    __syncthreads();
    if ((t & 63) == 0) { red[w] = s; red[4 + w] = q; }
    __syncthreads();
    s = red[0] + red[1] + red[2] + red[3];
    q = red[4] + red[5] + red[6] + red[7];
    float mean = s * (1.f / 2048.f);
    float var = q * (1.f / 2048.f) - mean * mean;
    float inv = rsqrtf(var + 1e-6f);
    const float* sc = part ? ksc : qsc;
    float extra = part ? 1.0f : 0.12751743f;  // (1/sqrt(128))*log2(e)
    s16x8 o;
#pragma unroll
    for (int j = 0; j < 8; j++) o[j] = (short)f2bf((f[j] - mean) * inv * (sc[t * 8 + j] * extra));
    *(s16x8*)p = o;
  }
}

// ------ v part of qkv (bf16) -> v_t [b][h][d][2048], PV-fragment order ------
// Within each 64-key tile, key (c*32+m*16+g*4+j) is stored at position
// (c*32+g*8+m*4+j), so a lane's 8 B-operand slots are one contiguous b128.
__global__ __launch_bounds__(256) void k_vT(const unsigned short* __restrict__ qkv,
                                            unsigned short* __restrict__ vt) {
  __shared__ unsigned short tl[64][136];
  const int bh = blockIdx.y;
  const int b = bh >> 4, h = bh & 15;
  const int s0 = blockIdx.x * 64;
  const int t = threadIdx.x;
#pragma unroll
  for (int it = 0; it < 4; ++it) {
    int flat = it * 256 + t;
    int r = flat >> 4, c = flat & 15;
    s16x8 v = *(const s16x8*)(qkv + (size_t)(b * 2048 + s0 + r) * 6144 + 4096 + h * 128 + c * 8);
    *((s16x8*)&tl[r][c * 8]) = v;
  }
  __syncthreads();
#pragma unroll
  for (int it = 0; it < 4; ++it) {
    int flat = it * 256 + t;
    int d = flat >> 3, cs = flat & 7;
    s16x8 o;
#pragma unroll
    for (int e = 0; e < 8; e++) {
      int key = (cs >> 2) * 32 + (e >> 2) * 16 + (cs & 3) * 4 + (e & 3);
      o[e] = (short)tl[key][d];
    }
    *(s16x8*)(vt + (size_t)(bh * 128 + d) * 2048 + s0 + cs * 8) = o;
  }
}

// --------------------------- causal flash attention -------------------------
// 4 waves x 16 q rows = 64-row Q tile; KV tiles of 64, double-buffered LDS
// with raw s_barrier + counted vmcnt (T3/T4): next tile's 8 global_load_lds
// stay in flight across barriers. Q held in registers. Each block processes
// the q-tile pair (31-pair, pair): exactly 33 tile-iterations per block.
// Swapped QK^T (mfma(K,Q)); P feeds PV A-operand straight from C-layout regs;
// V pre-permuted so PV B-operand is one b128 per half-tile. Defer-max (T13).
__global__ __launch_bounds__(256) void k_attn(const unsigned short* __restrict__ qkv,
                                              const unsigned short* __restrict__ vt,
                                              unsigned short* __restrict__ ctx) {
  __shared__ unsigned short sK[2][64 * 128];
  __shared__ unsigned short sV[2][128 * 64];
  const int t = threadIdx.x;
  const int w = t >> 6, lane = t & 63, g = lane >> 4, l15 = lane & 15;
  const int pair = blockIdx.x, h = blockIdx.y, b = blockIdx.z;
  const int qt0 = 31 - pair, qt1 = pair;
  const int n0 = qt0 + 1;            // iterations in segment 0
  const int NT = 33;                 // total iterations (n0 + qt1 + 1)
  const unsigned short* kbase = qkv + (size_t)(b * 2048) * 6144 + 2048 + h * 128;
  const unsigned short* vbase = vt + (size_t)((b * 16 + h) * 128) * 2048;

  auto issue_kv = [&](int k0, int bufi) {
#pragma unroll
    for (int it2 = 0; it2 < 4; ++it2) {       // K tile: 64 rows x 128d, swz c^(r&15)
      int flat = it2 * 256 + t;
      int r = flat >> 4, c = flat & 15;
      gload_lds16(kbase + (size_t)(k0 + r) * 6144 + ((c ^ (r & 15)) * 8),
                  (unsigned short*)&sK[bufi][(it2 * 256 + w * 64) * 8]);
    }
#pragma unroll
    for (int it2 = 0; it2 < 4; ++it2) {       // V tile: 128d x 64 keys, swz z^(d&7)
      int flat = it2 * 256 + t;
      int d = flat >> 3, z = flat & 7;
      gload_lds16(vbase + (size_t)d * 2048 + k0 + ((z ^ (d & 7)) * 8),
                  (unsigned short*)&sV[bufi][(it2 * 256 + w * 64) * 8]);
    }
  };

  s16x8 bq[4];
  auto load_q = [&](int q0) {
#pragma unroll
    for (int ks = 0; ks < 4; ++ks)
      bq[ks] = *(const s16x8*)(qkv + (size_t)(b * 2048 + q0 + w * 16 + l15) * 6144 +
                               h * 128 + (ks * 4 + g) * 8);
  };

  f32x4 o[8];
  float mrun, lrun;
  auto reset_state = [&]() {
#pragma unroll
    for (int nd = 0; nd < 8; ++nd) o[nd] = (f32x4){0.f, 0.f, 0.f, 0.f};
    mrun = -INFINITY; lrun = 0.f;
  };
  auto write_o = [&](int q0) {
    float ivr[4];
#pragma unroll
    for (int r = 0; r < 4; ++r) ivr[r] = 1.0f / __shfl(lrun, 4 * g + r);
#pragma unroll
    for (int nd = 0; nd < 8; ++nd) {
      const int col = h * 128 + nd * 16 + l15;
#pragma unroll
      for (int r = 0; r < 4; ++r) {
        const int row = b * 2048 + q0 + w * 16 + 4 * g + r;
        ctx[(size_t)row * 2048 + col] = f2bf(o[nd][r] * ivr[r]);
      }
    }
  };

  reset_state();
  load_q(qt0 * 64);
  issue_kv(0, 0);
  int cur = 0;

  for (int it = 0; it < NT; ++it) {
    const int seg = (it < n0) ? 0 : 1;
    const int qt = seg ? qt1 : qt0;
    const int kt = seg ? it - n0 : it;

    if (it + 1 < NT) {                               // prefetch next tile
      const int kn = (it + 1 < n0) ? it + 1 : it + 1 - n0;
      issue_kv(kn * 64, cur ^ 1);
      asm volatile("s_waitcnt vmcnt(8)" ::: "memory");   // current tile landed
    } else {
      asm volatile("s_waitcnt vmcnt(0)" ::: "memory");
    }
    __builtin_amdgcn_sched_barrier(0);
    __builtin_amdgcn_s_barrier();                    // all waves: tile visible

    if (seg == 1 && kt == 0) {                       // segment boundary
      write_o(qt0 * 64);
      reset_state();
      load_q(qt1 * 64);
    }

    const unsigned short* sKc = &sK[cur][0];
    const unsigned short* sVc = &sV[cur][0];

    f32x4 st[4];
#pragma unroll
    for (int mi = 0; mi < 4; ++mi) st[mi] = (f32x4){0.f, 0.f, 0.f, 0.f};
#pragma unroll
    for (int mi = 0; mi < 4; ++mi) {
#pragma unroll
      for (int ks = 0; ks < 4; ++ks) {
        s16x8 ak = *(const s16x8*)&sKc[(mi * 16 + l15) * 128 + (((ks * 4 + g) ^ l15) * 8)];
        st[mi] = __builtin_amdgcn_mfma_f32_16x16x32_bf16(ak, bq[ks], st[mi], 0, 0, 0);
      }
    }
    // st[mi][r] = S^T[key = mi*16+4g+r][q = w*16+l15] (pre-scaled, log2 domain)

    if (kt == qt) {                                  // diagonal: causal mask
      const int qloc = w * 16 + l15;
#pragma unroll
      for (int mi = 0; mi < 4; ++mi)
#pragma unroll
        for (int r = 0; r < 4; ++r)
          if (mi * 16 + 4 * g + r > qloc) st[mi][r] = -INFINITY;
    }

    float mt = -INFINITY;
#pragma unroll
    for (int mi = 0; mi < 4; ++mi)
#pragma unroll
      for (int r = 0; r < 4; ++r) mt = fmaxf(mt, st[mi][r]);
    mt = fmaxf(mt, __shfl_xor(mt, 16));
    mt = fmaxf(mt, __shfl_xor(mt, 32));

    if (!__all(mt <= mrun + 8.f)) {                  // defer-max: rescale rarely
      const float mnew = fmaxf(mrun, mt);
      const float alpha = exp2f(mrun - mnew);
      lrun *= alpha;
      float ar[4];
#pragma unroll
      for (int r = 0; r < 4; ++r) ar[r] = __shfl(alpha, 4 * g + r);
#pragma unroll
      for (int nd = 0; nd < 8; ++nd)
#pragma unroll
        for (int r = 0; r < 4; ++r) o[nd][r] *= ar[r];
      mrun = mnew;
    }

    float ls = 0.f;
#pragma unroll
    for (int mi = 0; mi < 4; ++mi)
#pragma unroll
      for (int r = 0; r < 4; ++r) {
        float pp = exp2f(st[mi][r] - mrun);
        st[mi][r] = pp;
        ls += pp;
      }
    ls += __shfl_xor(ls, 16);
    ls += __shfl_xor(ls, 32);
    lrun += ls;

    s16x8 pa01, pa23;  // P as PV A-operand: slot j <-> key (j>>2)*16+4g+(j&3) (+32 for pa23)
#pragma unroll
    for (int j = 0; j < 8; ++j) {
      pa01[j] = (short)f2bf(st[j >> 2][j & 3]);
      pa23[j] = (short)f2bf(st[2 + (j >> 2)][j & 3]);
    }

#pragma unroll
    for (int nd = 0; nd < 8; ++nd) {
      const int d = nd * 16 + l15;
      const int zs = d & 7;
      s16x8 bv0 = *(const s16x8*)&sVc[d * 64 + ((g ^ zs) * 8)];
      s16x8 bv1 = *(const s16x8*)&sVc[d * 64 + (((4 + g) ^ zs) * 8)];
      o[nd] = __builtin_amdgcn_mfma_f32_16x16x32_bf16(pa01, bv0, o[nd], 0, 0, 0);
      o[nd] = __builtin_amdgcn_mfma_f32_16x16x32_bf16(pa23, bv1, o[nd], 0, 0, 0);
    }

    __builtin_amdgcn_sched_barrier(0);
    __builtin_amdgcn_s_barrier();                    // reads of buf[cur] done
    cur ^= 1;
  }
  write_o(qt1 * 64);
}

// ---------------------------------------------------------------------------
extern "C" void kernel_launch(void* const* d_in, const int* in_sizes, int n_in,
                              void* d_out, int out_size, void* d_ws, size_t ws_size,
                              hipStream_t stream) {
  (void)in_sizes; (void)n_in; (void)out_size; (void)ws_size;
  const float* x    = (const float*)d_in[0];
  const float* Wqkv = (const float*)d_in[1];
  const float* qsc  = (const float*)d_in[2];
  const float* ksc  = (const float*)d_in[3];
  const float* outW = (const float*)d_in[4];

  char* ws = (char*)d_ws;
  unsigned short* xb  = (unsigned short*)(ws);              // 16.8MB (reused as ctx)
  unsigned short* wT  = (unsigned short*)(ws + 16777216);   // 25.2MB  Wqkv^T bf16
  unsigned short* owT = (unsigned short*)(ws + 41943040);   // 8.4MB   out_W^T bf16
  unsigned short* qkv = (unsigned short*)(ws + 50331648);   // 50.3MB  qkv bf16 (LN in place)
  unsigned short* vt  = (unsigned short*)(ws + 100663296);  // 16.8MB  v^T per head (PV-frag order)
  unsigned short* ctx = xb;                                 // x dead after QKV GEMM

  k_cvt4<<<8192, 256, 0, stream>>>((const float4*)x, (s16x4*)xb, 2097152);
  k_twT<<<dim3(192, 64), 256, 0, stream>>>(Wqkv, wT, 2048, 6144);
  k_twT<<<dim3(64, 64), 256, 0, stream>>>(outW, owT, 2048, 2048);
  k_gemm<1><<<dim3(48, 32), 256, 0, stream>>>(xb, wT, (void*)qkv, 4096, 6144, 2048);
  k_ln<<<4096, 256, 0, stream>>>(qkv, qsc, ksc);
  k_vT<<<dim3(32, 32), 256, 0, stream>>>(qkv, vt);
  k_attn<<<dim3(16, 16, 2), 256, 0, stream>>>(qkv, vt, ctx);
  k_gemm<0><<<dim3(16, 32), 256, 0, stream>>>(ctx, owT, d_out, 4096, 2048, 2048);
}

// Round 3
// 303.100 us; speedup vs baseline: 1.2572x; 1.0467x over previous
//
#include <hip/hip_runtime.h>

// ---------------------------------------------------------------------------
// FlaxAttention: x@Wqkv -> LN(q),LN(k) -> causal flash attn -> ctx@out_W
// B=2 S=2048 D=2048 H=16 Dh=128. All matmuls bf16 MFMA (fp32 accum).
// ---------------------------------------------------------------------------

typedef float f32x4 __attribute__((ext_vector_type(4)));
typedef short s16x8 __attribute__((ext_vector_type(8)));
typedef short s16x4 __attribute__((ext_vector_type(4)));

static __device__ __forceinline__ unsigned short f2bf(float f) {
  unsigned u = __builtin_bit_cast(unsigned, f);
  unsigned r = u + 0x7fffu + ((u >> 16) & 1u);   // RNE
  return (unsigned short)(r >> 16);
}
static __device__ __forceinline__ float bf2f(unsigned short s) {
  unsigned u = ((unsigned)s) << 16;
  return __builtin_bit_cast(float, u);
}

static __device__ __forceinline__ void gload_lds16(const unsigned short* g, unsigned short* l) {
  __builtin_amdgcn_global_load_lds((const __attribute__((address_space(1))) void*)g,
                                   (__attribute__((address_space(3))) void*)l, 16, 0, 0);
}

// --------------------------- fp32 -> bf16 convert ---------------------------
__global__ __launch_bounds__(256) void k_cvt4(const float4* __restrict__ in,
                                              s16x4* __restrict__ out, int n) {
  int i = blockIdx.x * 256 + threadIdx.x;
  if (i >= n) return;
  float4 v = in[i];
  s16x4 o = { (short)f2bf(v.x), (short)f2bf(v.y), (short)f2bf(v.z), (short)f2bf(v.w) };
  out[i] = o;
}

// ------------------- W [K][N] f32 -> W^T [N][K] bf16 ------------------------
__global__ __launch_bounds__(256) void k_twT(const float* __restrict__ in,
                                             unsigned short* __restrict__ out,
                                             int K, int N) {
  __shared__ float tile[32][33];
  const int n0 = blockIdx.x * 32, k0 = blockIdx.y * 32;
  const int tx = threadIdx.x & 31, ty = threadIdx.x >> 5;
#pragma unroll
  for (int rr = 0; rr < 4; ++rr) {
    int kr = ty + rr * 8;
    tile[kr][tx] = in[(size_t)(k0 + kr) * N + n0 + tx];
  }
  __syncthreads();
#pragma unroll
  for (int rr = 0; rr < 4; ++rr) {
    int nr = ty + rr * 8;
    out[(size_t)(n0 + nr) * K + k0 + tx] = f2bf(tile[tx][nr]);
  }
}

// ---------------- 256x256 8-phase GEMM (bf16 out), BK=64 --------------------
// C[M][N] = A[M][K] * Bt[N][K]^T. 8 waves (2Mx4N), per-wave C = 128x64.
// Per K-tile: 4 phases, each = one 128x128 C-quadrant over K=64 (16 MFMA/wave)
// with {12,4,8,0} ds_read_b128 + one half-tile global_load_lds stage + 2 raw
// barriers. Counted vmcnt (8 at q1, 6 at q3) -- never 0 mid-loop.
// Stage stream per tile s: [q0:B1(s+1)][q1:A1(s+1)][q2:A0(s+2)][q3:B0(s+2)].
//   q1 wait vmcnt(8): newest 4 halves outstanding => A1(s) landed (read @q2).
//   q3 wait vmcnt(6): newest 3 outstanding => A0/B0/B1(s+1) landed (read @q0/q1).
// Overwrite safety: each stage targets a region whose last ds_read finished
// >= 2 barriers before the stage issue (verified per-region).
// LDS swizzle: 16B-slot ^= (row&7); global source pre-swizzled (rule #21).
__global__ __launch_bounds__(512, 2) void k_gemm256(const unsigned short* __restrict__ A,
                                                    const unsigned short* __restrict__ Bt,
                                                    unsigned short* __restrict__ Cout,
                                                    int N, int K, int nbn) {
  __shared__ unsigned short sA[2 * 2 * 128 * 64];  // [buf][half][128][64] 64KB
  __shared__ unsigned short sB[2 * 2 * 128 * 64];
  const int t = threadIdx.x;
  const int wid = t >> 6, lane = t & 63, g = lane >> 4, l15 = lane & 15;
  const int wm2 = wid >> 2, wn2 = wid & 3;
  const int xr = l15 & 7;

  // XCD-aware bijective swizzle (gridDim.x % 8 == 0)
  const int cpx = (int)gridDim.x >> 3;
  const int swz = ((int)blockIdx.x & 7) * cpx + ((int)blockIdx.x >> 3);
  const int m0 = (swz / nbn) * 256, n0 = (swz % nbn) * 256;

  // staging: thread covers (row = t>>3 within half [+64 for j=1], 16B slot)
  const int srow = t >> 3;
  const int sslot = (t & 7) ^ (srow & 7);          // pre-swizzled source slot
  const unsigned short* pA = A  + (size_t)(m0 + srow) * K + sslot * 8;
  const unsigned short* pB = Bt + (size_t)(n0 + srow) * K + sslot * 8;
  const int ldsb = wid * 512;                      // per-wave dest (elements)

  auto stageA = [&](int kt, int h) {
#pragma unroll
    for (int j = 0; j < 2; ++j)
      gload_lds16(pA + (size_t)(h * 128 + j * 64) * K + kt * 64,
                  sA + ((kt & 1) * 2 + h) * 8192 + j * 4096 + ldsb);
  };
  auto stageB = [&](int kt, int h) {
#pragma unroll
    for (int j = 0; j < 2; ++j)
      gload_lds16(pB + (size_t)(h * 128 + j * 64) * K + kt * 64,
                  sB + ((kt & 1) * 2 + h) * 8192 + j * 4096 + ldsb);
  };

  const int arow = wm2 * 64 + l15;                 // + fm*16, within A-half
  const int brow = wn2 * 32 + l15;                 // + fn*16, within B-half
  const int sl0 = (g ^ xr) * 8, sl1 = ((4 + g) ^ xr) * 8;  // ks=0,1 slots

  f32x4 acc[2][2][4][2];
#pragma unroll
  for (int a = 0; a < 2; ++a)
#pragma unroll
    for (int b = 0; b < 2; ++b)
#pragma unroll
      for (int c = 0; c < 4; ++c)
#pragma unroll
        for (int d = 0; d < 2; ++d) acc[a][b][c][d] = (f32x4){0.f, 0.f, 0.f, 0.f};

  const int NK = K >> 6;
  // prologue: A0(0) B0(0) B1(0) A1(0) A0(1) B0(1), then all-but-3 landed.
  stageA(0, 0); stageB(0, 0); stageB(0, 1); stageA(0, 1); stageA(1, 0); stageB(1, 0);
  asm volatile("s_waitcnt vmcnt(6)" ::: "memory");
  __builtin_amdgcn_sched_barrier(0);
  asm volatile("s_barrier" ::: "memory");

  for (int s = 0; s < NK; ++s) {
    const unsigned short* aT = sA + (s & 1) * 16384;
    const unsigned short* bT = sB + (s & 1) * 16384;
    const bool tail = (s >= NK - 2);
    s16x8 af[4][2], bf0[2][2], bf1[2][2];

    // ---------------- q0: quadrant (0,0) ----------------
#pragma unroll
    for (int fm = 0; fm < 4; ++fm) {
      af[fm][0] = *(const s16x8*)&aT[(arow + fm * 16) * 64 + sl0];
      af[fm][1] = *(const s16x8*)&aT[(arow + fm * 16) * 64 + sl1];
    }
#pragma unroll
    for (int fn = 0; fn < 2; ++fn) {
      bf0[fn][0] = *(const s16x8*)&bT[(brow + fn * 16) * 64 + sl0];
      bf0[fn][1] = *(const s16x8*)&bT[(brow + fn * 16) * 64 + sl1];
    }
    if (s + 1 < NK) stageB(s + 1, 1);
    asm volatile("s_barrier" ::: "memory");
    __builtin_amdgcn_s_setprio(1);
#pragma unroll
    for (int fm = 0; fm < 4; ++fm)
#pragma unroll
      for (int fn = 0; fn < 2; ++fn)
#pragma unroll
        for (int ks = 0; ks < 2; ++ks)
          acc[0][0][fm][fn] = __builtin_amdgcn_mfma_f32_16x16x32_bf16(
              af[fm][ks], bf0[fn][ks], acc[0][0][fm][fn], 0, 0, 0);
    __builtin_amdgcn_s_setprio(0);
    asm volatile("s_barrier" ::: "memory");

    // ---------------- q1: quadrant (0,1) ----------------
#pragma unroll
    for (int fn = 0; fn < 2; ++fn) {
      bf1[fn][0] = *(const s16x8*)&bT[8192 + (brow + fn * 16) * 64 + sl0];
      bf1[fn][1] = *(const s16x8*)&bT[8192 + (brow + fn * 16) * 64 + sl1];
    }
    if (s + 1 < NK) stageA(s + 1, 1);
    if (tail) asm volatile("s_waitcnt vmcnt(0)" ::: "memory");
    else      asm volatile("s_waitcnt vmcnt(8)" ::: "memory");
    __builtin_amdgcn_sched_barrier(0);
    asm volatile("s_barrier" ::: "memory");
    __builtin_amdgcn_s_setprio(1);
#pragma unroll
    for (int fm = 0; fm < 4; ++fm)
#pragma unroll
      for (int fn = 0; fn < 2; ++fn)
#pragma unroll
        for (int ks = 0; ks < 2; ++ks)
          acc[0][1][fm][fn] = __builtin_amdgcn_mfma_f32_16x16x32_bf16(
              af[fm][ks], bf1[fn][ks], acc[0][1][fm][fn], 0, 0, 0);
    __builtin_amdgcn_s_setprio(0);
    asm volatile("s_barrier" ::: "memory");

    // ---------------- q2: quadrant (1,0) ----------------
#pragma unroll
    for (int fm = 0; fm < 4; ++fm) {
      af[fm][0] = *(const s16x8*)&aT[8192 + (arow + fm * 16) * 64 + sl0];
      af[fm][1] = *(const s16x8*)&aT[8192 + (arow + fm * 16) * 64 + sl1];
    }
    if (s + 2 < NK) stageA(s + 2, 0);
    asm volatile("s_barrier" ::: "memory");
    __builtin_amdgcn_s_setprio(1);
#pragma unroll
    for (int fm = 0; fm < 4; ++fm)
#pragma unroll
      for (int fn = 0; fn < 2; ++fn)
#pragma unroll
        for (int ks = 0; ks < 2; ++ks)
          acc[1][0][fm][fn] = __builtin_amdgcn_mfma_f32_16x16x32_bf16(
              af[fm][ks], bf0[fn][ks], acc[1][0][fm][fn], 0, 0, 0);
    __builtin_amdgcn_s_setprio(0);
    asm volatile("s_barrier" ::: "memory");

    // ---------------- q3: quadrant (1,1) ----------------
    if (s + 2 < NK) stageB(s + 2, 0);
    if (tail) asm volatile("s_waitcnt vmcnt(0)" ::: "memory");
    else      asm volatile("s_waitcnt vmcnt(6)" ::: "memory");
    __builtin_amdgcn_sched_barrier(0);
    asm volatile("s_barrier" ::: "memory");
    __builtin_amdgcn_s_setprio(1);
#pragma unroll
    for (int fm = 0; fm < 4; ++fm)
#pragma unroll
      for (int fn = 0; fn < 2; ++fn)
#pragma unroll
        for (int ks = 0; ks < 2; ++ks)
          acc[1][1][fm][fn] = __builtin_amdgcn_mfma_f32_16x16x32_bf16(
              af[fm][ks], bf1[fn][ks], acc[1][1][fm][fn], 0, 0, 0);
    __builtin_amdgcn_s_setprio(0);
    asm volatile("s_barrier" ::: "memory");
  }

  // epilogue: C write (bf16)
#pragma unroll
  for (int qm = 0; qm < 2; ++qm)
#pragma unroll
    for (int qn = 0; qn < 2; ++qn)
#pragma unroll
      for (int fm = 0; fm < 4; ++fm)
#pragma unroll
        for (int fn = 0; fn < 2; ++fn)
#pragma unroll
          for (int r = 0; r < 4; ++r) {
            const int row = m0 + qm * 128 + wm2 * 64 + fm * 16 + g * 4 + r;
            const int col = n0 + qn * 128 + wn2 * 32 + fn * 16 + l15;
            Cout[(size_t)row * N + col] = f2bf(acc[qm][qn][fm][fn][r]);
          }
}

// --------------- GEMM C[M][N] = A[M][K] * Bt[N][K]^T (bf16 MFMA) ------------
// 128x128 tile, BK=32, 4 waves (2x2) -- used for the out-projection.
template <int BF16OUT>
__global__ __launch_bounds__(256) void k_gemm(const unsigned short* __restrict__ A,
                                              const unsigned short* __restrict__ Bt,
                                              void* __restrict__ Cout,
                                              int M, int N, int K) {
  __shared__ unsigned short sA[128 * 32];
  __shared__ unsigned short sB[128 * 32];
  const int t = threadIdx.x;
  const int w = t >> 6, lane = t & 63, g = lane >> 4, l15 = lane & 15;
  const int m0 = blockIdx.y * 128, n0 = blockIdx.x * 128;
  const int wm = (w >> 1) * 64, wn = (w & 1) * 64;
  f32x4 acc[4][4];
#pragma unroll
  for (int i = 0; i < 4; i++)
#pragma unroll
    for (int j = 0; j < 4; j++) acc[i][j] = (f32x4){0.f, 0.f, 0.f, 0.f};

  const int nk = K >> 5;
  for (int kt = 0; kt < nk; ++kt) {
    __syncthreads();
#pragma unroll
    for (int it = 0; it < 2; ++it) {
      int flat = it * 256 + t;
      int row = flat >> 2, ch = flat & 3;
      gload_lds16(A  + (size_t)(m0 + row) * K + kt * 32 + ch * 8,
                  sA + (size_t)(it * 256 + w * 64) * 8);
      gload_lds16(Bt + (size_t)(n0 + row) * K + kt * 32 + ch * 8,
                  sB + (size_t)(it * 256 + w * 64) * 8);
    }
    __syncthreads();
    s16x8 af[4], bf[4];
#pragma unroll
    for (int i = 0; i < 4; i++) {
      af[i] = *(const s16x8*)&sA[(wm + i * 16 + l15) * 32 + 8 * g];
      bf[i] = *(const s16x8*)&sB[(wn + i * 16 + l15) * 32 + 8 * g];
    }
#pragma unroll
    for (int i = 0; i < 4; i++)
#pragma unroll
      for (int j = 0; j < 4; j++)
        acc[i][j] = __builtin_amdgcn_mfma_f32_16x16x32_bf16(af[i], bf[j], acc[i][j], 0, 0, 0);
  }
#pragma unroll
  for (int i = 0; i < 4; i++) {
#pragma unroll
    for (int j = 0; j < 4; j++) {
#pragma unroll
      for (int r = 0; r < 4; r++) {
        int row = m0 + wm + i * 16 + 4 * g + r;
        int col = n0 + wn + j * 16 + l15;
        if (BF16OUT)
          ((unsigned short*)Cout)[(size_t)row * N + col] = f2bf(acc[i][j][r]);
        else
          ((float*)Cout)[(size_t)row * N + col] = acc[i][j][r];
      }
    }
  }
}

// ----------------- in-place LayerNorm on q,k parts of qkv -------------------
// q gets *= q_scale * (1/sqrt(128))*log2(e) so attn uses exp2 directly.
__global__ __launch_bounds__(256) void k_ln(unsigned short* __restrict__ qkv,
                                            const float* __restrict__ qsc,
                                            const float* __restrict__ ksc) {
  __shared__ float red[8];
  const int t = threadIdx.x;
  const int w = t >> 6;
  unsigned short* base = qkv + (size_t)blockIdx.x * 6144;
#pragma unroll
  for (int part = 0; part < 2; ++part) {
    unsigned short* p = base + part * 2048 + t * 8;
    s16x8 v = *(const s16x8*)p;
    float f[8], s = 0.f, q = 0.f;
#pragma unroll
    for (int j = 0; j < 8; j++) { f[j] = bf2f((unsigned short)v[j]); s += f[j]; q += f[j] * f[j]; }
#pragma unroll
    for (int m = 1; m < 64; m <<= 1) { s += __shfl_xor(s, m); q += __shfl_xor(q, m); }
    __syncthreads();
    if ((t & 63) == 0) { red[w] = s; red[4 + w] = q; }
    __syncthreads();
    s = red[0] + red[1] + red[2] + red[3];
    q = red[4] + red[5] + red[6] + red[7];
    float mean = s * (1.f / 2048.f);
    float var = q * (1.f / 2048.f) - mean * mean;
    float inv = rsqrtf(var + 1e-6f);
    const float* sc = part ? ksc : qsc;
    float extra = part ? 1.0f : 0.12751743f;  // (1/sqrt(128))*log2(e)
    s16x8 o;
#pragma unroll
    for (int j = 0; j < 8; j++) o[j] = (short)f2bf((f[j] - mean) * inv * (sc[t * 8 + j] * extra));
    *(s16x8*)p = o;
  }
}

// ------ v part of qkv (bf16) -> v_t [b][h][d][2048], PV-fragment order ------
__global__ __launch_bounds__(256) void k_vT(const unsigned short* __restrict__ qkv,
                                            unsigned short* __restrict__ vt) {
  __shared__ unsigned short tl[64][136];
  const int bh = blockIdx.y;
  const int b = bh >> 4, h = bh & 15;
  const int s0 = blockIdx.x * 64;
  const int t = threadIdx.x;
#pragma unroll
  for (int it = 0; it < 4; ++it) {
    int flat = it * 256 + t;
    int r = flat >> 4, c = flat & 15;
    s16x8 v = *(const s16x8*)(qkv + (size_t)(b * 2048 + s0 + r) * 6144 + 4096 + h * 128 + c * 8);
    *((s16x8*)&tl[r][c * 8]) = v;
  }
  __syncthreads();
#pragma unroll
  for (int it = 0; it < 4; ++it) {
    int flat = it * 256 + t;
    int d = flat >> 3, cs = flat & 7;
    s16x8 o;
#pragma unroll
    for (int e = 0; e < 8; e++) {
      int key = (cs >> 2) * 32 + (e >> 2) * 16 + (cs & 3) * 4 + (e & 3);
      o[e] = (short)tl[key][d];
    }
    *(s16x8*)(vt + (size_t)(bh * 128 + d) * 2048 + s0 + cs * 8) = o;
  }
}

// --------------------------- causal flash attention -------------------------
__global__ __launch_bounds__(256) void k_attn(const unsigned short* __restrict__ qkv,
                                              const unsigned short* __restrict__ vt,
                                              unsigned short* __restrict__ ctx) {
  __shared__ unsigned short sK[2][64 * 128];
  __shared__ unsigned short sV[2][128 * 64];
  const int t = threadIdx.x;
  const int w = t >> 6, lane = t & 63, g = lane >> 4, l15 = lane & 15;
  const int pair = blockIdx.x, h = blockIdx.y, b = blockIdx.z;
  const int qt0 = 31 - pair, qt1 = pair;
  const int n0 = qt0 + 1;
  const int NT = 33;
  const unsigned short* kbase = qkv + (size_t)(b * 2048) * 6144 + 2048 + h * 128;
  const unsigned short* vbase = vt + (size_t)((b * 16 + h) * 128) * 2048;

  auto issue_kv = [&](int k0, int bufi) {
#pragma unroll
    for (int it2 = 0; it2 < 4; ++it2) {
      int flat = it2 * 256 + t;
      int r = flat >> 4, c = flat & 15;
      gload_lds16(kbase + (size_t)(k0 + r) * 6144 + ((c ^ (r & 15)) * 8),
                  (unsigned short*)&sK[bufi][(it2 * 256 + w * 64) * 8]);
    }
#pragma unroll
    for (int it2 = 0; it2 < 4; ++it2) {
      int flat = it2 * 256 + t;
      int d = flat >> 3, z = flat & 7;
      gload_lds16(vbase + (size_t)d * 2048 + k0 + ((z ^ (d & 7)) * 8),
                  (unsigned short*)&sV[bufi][(it2 * 256 + w * 64) * 8]);
    }
  };

  s16x8 bq[4];
  auto load_q = [&](int q0) {
#pragma unroll
    for (int ks = 0; ks < 4; ++ks)
      bq[ks] = *(const s16x8*)(qkv + (size_t)(b * 2048 + q0 + w * 16 + l15) * 6144 +
                               h * 128 + (ks * 4 + g) * 8);
  };

  f32x4 o[8];
  float mrun, lrun;
  auto reset_state = [&]() {
#pragma unroll
    for (int nd = 0; nd < 8; ++nd) o[nd] = (f32x4){0.f, 0.f, 0.f, 0.f};
    mrun = -INFINITY; lrun = 0.f;
  };
  auto write_o = [&](int q0) {
    float ivr[4];
#pragma unroll
    for (int r = 0; r < 4; ++r) ivr[r] = 1.0f / __shfl(lrun, 4 * g + r);
#pragma unroll
    for (int nd = 0; nd < 8; ++nd) {
      const int col = h * 128 + nd * 16 + l15;
#pragma unroll
      for (int r = 0; r < 4; ++r) {
        const int row = b * 2048 + q0 + w * 16 + 4 * g + r;
        ctx[(size_t)row * 2048 + col] = f2bf(o[nd][r] * ivr[r]);
      }
    }
  };

  reset_state();
  load_q(qt0 * 64);
  issue_kv(0, 0);
  int cur = 0;

  for (int it = 0; it < NT; ++it) {
    const int seg = (it < n0) ? 0 : 1;
    const int qt = seg ? qt1 : qt0;
    const int kt = seg ? it - n0 : it;

    if (it + 1 < NT) {
      const int kn = (it + 1 < n0) ? it + 1 : it + 1 - n0;
      issue_kv(kn * 64, cur ^ 1);
      asm volatile("s_waitcnt vmcnt(8)" ::: "memory");
    } else {
      asm volatile("s_waitcnt vmcnt(0)" ::: "memory");
    }
    __builtin_amdgcn_sched_barrier(0);
    __builtin_amdgcn_s_barrier();

    if (seg == 1 && kt == 0) {
      write_o(qt0 * 64);
      reset_state();
      load_q(qt1 * 64);
    }

    const unsigned short* sKc = &sK[cur][0];
    const unsigned short* sVc = &sV[cur][0];

    f32x4 st[4];
#pragma unroll
    for (int mi = 0; mi < 4; ++mi) st[mi] = (f32x4){0.f, 0.f, 0.f, 0.f};
#pragma unroll
    for (int mi = 0; mi < 4; ++mi) {
#pragma unroll
      for (int ks = 0; ks < 4; ++ks) {
        s16x8 ak = *(const s16x8*)&sKc[(mi * 16 + l15) * 128 + (((ks * 4 + g) ^ l15) * 8)];
        st[mi] = __builtin_amdgcn_mfma_f32_16x16x32_bf16(ak, bq[ks], st[mi], 0, 0, 0);
      }
    }

    if (kt == qt) {
      const int qloc = w * 16 + l15;
#pragma unroll
      for (int mi = 0; mi < 4; ++mi)
#pragma unroll
        for (int r = 0; r < 4; ++r)
          if (mi * 16 + 4 * g + r > qloc) st[mi][r] = -INFINITY;
    }

    float mt = -INFINITY;
#pragma unroll
    for (int mi = 0; mi < 4; ++mi)
#pragma unroll
      for (int r = 0; r < 4; ++r) mt = fmaxf(mt, st[mi][r]);
    mt = fmaxf(mt, __shfl_xor(mt, 16));
    mt = fmaxf(mt, __shfl_xor(mt, 32));

    if (!__all(mt <= mrun + 8.f)) {
      const float mnew = fmaxf(mrun, mt);
      const float alpha = exp2f(mrun - mnew);
      lrun *= alpha;
      float ar[4];
#pragma unroll
      for (int r = 0; r < 4; ++r) ar[r] = __shfl(alpha, 4 * g + r);
#pragma unroll
      for (int nd = 0; nd < 8; ++nd)
#pragma unroll
        for (int r = 0; r < 4; ++r) o[nd][r] *= ar[r];
      mrun = mnew;
    }

    float ls = 0.f;
#pragma unroll
    for (int mi = 0; mi < 4; ++mi)
#pragma unroll
      for (int r = 0; r < 4; ++r) {
        float pp = exp2f(st[mi][r] - mrun);
        st[mi][r] = pp;
        ls += pp;
      }
    ls += __shfl_xor(ls, 16);
    ls += __shfl_xor(ls, 32);
    lrun += ls;

    s16x8 pa01, pa23;
#pragma unroll
    for (int j = 0; j < 8; ++j) {
      pa01[j] = (short)f2bf(st[j >> 2][j & 3]);
      pa23[j] = (short)f2bf(st[2 + (j >> 2)][j & 3]);
    }

#pragma unroll
    for (int nd = 0; nd < 8; ++nd) {
      const int d = nd * 16 + l15;
      const int zs = d & 7;
      s16x8 bv0 = *(const s16x8*)&sVc[d * 64 + ((g ^ zs) * 8)];
      s16x8 bv1 = *(const s16x8*)&sVc[d * 64 + (((4 + g) ^ zs) * 8)];
      o[nd] = __builtin_amdgcn_mfma_f32_16x16x32_bf16(pa01, bv0, o[nd], 0, 0, 0);
      o[nd] = __builtin_amdgcn_mfma_f32_16x16x32_bf16(pa23, bv1, o[nd], 0, 0, 0);
    }

    __builtin_amdgcn_sched_barrier(0);
    __builtin_amdgcn_s_barrier();
    cur ^= 1;
  }
  write_o(qt1 * 64);
}

// ---------------------------------------------------------------------------
extern "C" void kernel_launch(void* const* d_in, const int* in_sizes, int n_in,
                              void* d_out, int out_size, void* d_ws, size_t ws_size,
                              hipStream_t stream) {
  (void)in_sizes; (void)n_in; (void)out_size; (void)ws_size;
  const float* x    = (const float*)d_in[0];
  const float* Wqkv = (const float*)d_in[1];
  const float* qsc  = (const float*)d_in[2];
  const float* ksc  = (const float*)d_in[3];
  const float* outW = (const float*)d_in[4];

  char* ws = (char*)d_ws;
  unsigned short* xb  = (unsigned short*)(ws);              // 16.8MB (reused as ctx)
  unsigned short* wT  = (unsigned short*)(ws + 16777216);   // 25.2MB  Wqkv^T bf16
  unsigned short* owT = (unsigned short*)(ws + 41943040);   // 8.4MB   out_W^T bf16
  unsigned short* qkv = (unsigned short*)(ws + 50331648);   // 50.3MB  qkv bf16 (LN in place)
  unsigned short* vt  = (unsigned short*)(ws + 100663296);  // 16.8MB  v^T per head
  unsigned short* ctx = xb;                                 // x dead after QKV GEMM

  k_cvt4<<<8192, 256, 0, stream>>>((const float4*)x, (s16x4*)xb, 2097152);
  k_twT<<<dim3(192, 64), 256, 0, stream>>>(Wqkv, wT, 2048, 6144);
  k_twT<<<dim3(64, 64), 256, 0, stream>>>(outW, owT, 2048, 2048);
  k_gemm256<<<384, 512, 0, stream>>>(xb, wT, qkv, 6144, 2048, 24);
  k_ln<<<4096, 256, 0, stream>>>(qkv, qsc, ksc);
  k_vT<<<dim3(32, 32), 256, 0, stream>>>(qkv, vt);
  k_attn<<<dim3(16, 16, 2), 256, 0, stream>>>(qkv, vt, ctx);
  k_gemm<0><<<dim3(16, 32), 256, 0, stream>>>(ctx, owT, d_out, 4096, 2048, 2048);
}

// Round 4
// 280.819 us; speedup vs baseline: 1.3569x; 1.0793x over previous
//
#include <hip/hip_runtime.h>

// ---------------------------------------------------------------------------
// FlaxAttention: x@Wqkv -> LN(q),LN(k) -> causal flash attn -> ctx@out_W
// B=2 S=2048 D=2048 H=16 Dh=128. All matmuls bf16 MFMA (fp32 accum).
// ---------------------------------------------------------------------------

typedef float f32x4 __attribute__((ext_vector_type(4)));
typedef short s16x8 __attribute__((ext_vector_type(8)));
typedef short s16x4 __attribute__((ext_vector_type(4)));

static __device__ __forceinline__ unsigned short f2bf(float f) {
  unsigned u = __builtin_bit_cast(unsigned, f);
  unsigned r = u + 0x7fffu + ((u >> 16) & 1u);   // RNE
  return (unsigned short)(r >> 16);
}
static __device__ __forceinline__ float bf2f(unsigned short s) {
  unsigned u = ((unsigned)s) << 16;
  return __builtin_bit_cast(float, u);
}

static __device__ __forceinline__ void gload_lds16(const unsigned short* g, unsigned short* l) {
  __builtin_amdgcn_global_load_lds((const __attribute__((address_space(1))) void*)g,
                                   (__attribute__((address_space(3))) void*)l, 16, 0, 0);
}

// --------------------------- fp32 -> bf16 convert ---------------------------
__global__ __launch_bounds__(256) void k_cvt4(const float4* __restrict__ in,
                                              s16x4* __restrict__ out, int n) {
  int i = blockIdx.x * 256 + threadIdx.x;
  if (i >= n) return;
  float4 v = in[i];
  s16x4 o = { (short)f2bf(v.x), (short)f2bf(v.y), (short)f2bf(v.z), (short)f2bf(v.w) };
  out[i] = o;
}

// ------------------- W [K][N] f32 -> W^T [N][K] bf16 ------------------------
__global__ __launch_bounds__(256) void k_twT(const float* __restrict__ in,
                                             unsigned short* __restrict__ out,
                                             int K, int N) {
  __shared__ float tile[32][33];
  const int n0 = blockIdx.x * 32, k0 = blockIdx.y * 32;
  const int tx = threadIdx.x & 31, ty = threadIdx.x >> 5;
#pragma unroll
  for (int rr = 0; rr < 4; ++rr) {
    int kr = ty + rr * 8;
    tile[kr][tx] = in[(size_t)(k0 + kr) * N + n0 + tx];
  }
  __syncthreads();
#pragma unroll
  for (int rr = 0; rr < 4; ++rr) {
    int nr = ty + rr * 8;
    out[(size_t)(n0 + nr) * K + k0 + tx] = f2bf(tile[tx][nr]);
  }
}

// ------------- 128x256 2-phase pipelined GEMM, BK=64 (bf16 MFMA) ------------
// C[M][N] = A[M][K] * Bt[N][K]^T. 8 waves (2Mx4N), per-wave C = 64x64.
// Grid = (M/128)*(N/256): QKV -> 768 (= 3 exact rounds of 256 CUs),
// out-proj -> 256 (= 1 exact round). LDS 96KB (1 block/CU).
// Per K-tile: 2 phases. p0 = C cols [0,128) (A frags + B-half0, 16 MFMA/wave),
// p1 = C cols [128,256) (B-half1, A frags reused from registers).
// Stage stream (tile s): p0 issues {A(s+1), B0(s+1)} then vmcnt(4);
// p1 issues {B1(s+1)} then vmcnt(2). Proof of deadlines:
//   p1(s-1) vmcnt(2): newest 2 (B1(s)) outstanding => A(s),B0(s) landed,
//     read at p0(s) after p1(s-1)'s end barrier.            [OK]
//   p0(s) vmcnt(4): newest 4 (A(s+1),B0(s+1)) outstanding => B1(s) landed,
//     read at p1(s) after p0(s)'s end barrier.              [OK]
// Overwrite safety: each stage's LDS region was last ds_read 3 barriers
// earlier (read completion forced before that phase's MFMA/barrier).
// LDS swizzle: 16B-slot ^= (row&7), source pre-swizzled (rule #21).
template <int BF16OUT>
__global__ __launch_bounds__(512, 2) void k_g8p(const unsigned short* __restrict__ A,
                                                const unsigned short* __restrict__ Bt,
                                                void* __restrict__ Cout,
                                                int N, int K, int nbn) {
  __shared__ unsigned short sA[2 * 128 * 64];       // 32KB [buf][128][64]
  __shared__ unsigned short sB[2 * 2 * 128 * 64];   // 64KB [buf][half][128][64]
  const int t = threadIdx.x;
  const int wid = t >> 6, lane = t & 63, g = lane >> 4, l15 = lane & 15;
  const int wm2 = wid >> 2, wn2 = wid & 3;
  const int xr = l15 & 7;

  // XCD-aware bijective swizzle (gridDim.x % 8 == 0)
  const int cpx = (int)gridDim.x >> 3;
  const int swz = ((int)blockIdx.x & 7) * cpx + ((int)blockIdx.x >> 3);
  const int m0 = (swz / nbn) * 128, n0 = (swz % nbn) * 256;

  // staging: thread -> (row = j*64 + (t>>3), 16B slot t&7), source pre-swizzled
  const int srow = t >> 3;
  const int sslot = (t & 7) ^ (srow & 7);           // (row&7) == (srow&7)
  const unsigned short* pA = A  + (size_t)(m0 + srow) * K + sslot * 8;
  const unsigned short* pB = Bt + (size_t)(n0 + srow) * K + sslot * 8;

  auto stageA = [&](int kt) {
#pragma unroll
    for (int j = 0; j < 2; ++j)
      gload_lds16(pA + (size_t)(j * 64) * K + kt * 64,
                  sA + (kt & 1) * 8192 + j * 4096 + t * 8);
  };
  auto stageB = [&](int kt, int h) {
#pragma unroll
    for (int j = 0; j < 2; ++j)
      gload_lds16(pB + (size_t)(h * 128 + j * 64) * K + kt * 64,
                  sB + (kt & 1) * 16384 + h * 8192 + j * 4096 + t * 8);
  };

  const int sl0 = (g ^ xr) * 8, sl1 = ((4 + g) ^ xr) * 8;   // ks=0,1 slots
  const int arow = wm2 * 64 + l15;                  // + fm*16
  const int brow = wn2 * 32 + l15;                  // + fn*16, within half

  f32x4 acc[2][4][2];
#pragma unroll
  for (int h = 0; h < 2; ++h)
#pragma unroll
    for (int fm = 0; fm < 4; ++fm)
#pragma unroll
      for (int fn = 0; fn < 2; ++fn) acc[h][fm][fn] = (f32x4){0.f, 0.f, 0.f, 0.f};

  const int NK = K >> 6;
  stageA(0); stageB(0, 0); stageB(0, 1);
  asm volatile("s_waitcnt vmcnt(2)" ::: "memory");
  __builtin_amdgcn_sched_barrier(0);
  asm volatile("s_barrier" ::: "memory");

  for (int s = 0; s < NK; ++s) {
    const unsigned short* aT = sA + (s & 1) * 8192;
    const unsigned short* bT = sB + (s & 1) * 16384;
    const bool tail = (s == NK - 1);
    s16x8 af[4][2], bfr[2][2];

    // ---------------- p0: C cols [0,128) ----------------
#pragma unroll
    for (int fm = 0; fm < 4; ++fm) {
      af[fm][0] = *(const s16x8*)&aT[(arow + fm * 16) * 64 + sl0];
      af[fm][1] = *(const s16x8*)&aT[(arow + fm * 16) * 64 + sl1];
    }
#pragma unroll
    for (int fn = 0; fn < 2; ++fn) {
      bfr[fn][0] = *(const s16x8*)&bT[(brow + fn * 16) * 64 + sl0];
      bfr[fn][1] = *(const s16x8*)&bT[(brow + fn * 16) * 64 + sl1];
    }
    if (!tail) { stageA(s + 1); stageB(s + 1, 0); }
    if (tail) asm volatile("s_waitcnt vmcnt(0)" ::: "memory");
    else      asm volatile("s_waitcnt vmcnt(4)" ::: "memory");
    __builtin_amdgcn_sched_barrier(0);
    asm volatile("s_barrier" ::: "memory");
    __builtin_amdgcn_s_setprio(1);
#pragma unroll
    for (int fm = 0; fm < 4; ++fm)
#pragma unroll
      for (int fn = 0; fn < 2; ++fn)
#pragma unroll
        for (int ks = 0; ks < 2; ++ks)
          acc[0][fm][fn] = __builtin_amdgcn_mfma_f32_16x16x32_bf16(
              af[fm][ks], bfr[fn][ks], acc[0][fm][fn], 0, 0, 0);
    __builtin_amdgcn_s_setprio(0);
    asm volatile("s_barrier" ::: "memory");

    // ---------------- p1: C cols [128,256) --------------
#pragma unroll
    for (int fn = 0; fn < 2; ++fn) {
      bfr[fn][0] = *(const s16x8*)&bT[8192 + (brow + fn * 16) * 64 + sl0];
      bfr[fn][1] = *(const s16x8*)&bT[8192 + (brow + fn * 16) * 64 + sl1];
    }
    if (!tail) stageB(s + 1, 1);
    if (tail) asm volatile("s_waitcnt vmcnt(0)" ::: "memory");
    else      asm volatile("s_waitcnt vmcnt(2)" ::: "memory");
    __builtin_amdgcn_sched_barrier(0);
    asm volatile("s_barrier" ::: "memory");
    __builtin_amdgcn_s_setprio(1);
#pragma unroll
    for (int fm = 0; fm < 4; ++fm)
#pragma unroll
      for (int fn = 0; fn < 2; ++fn)
#pragma unroll
        for (int ks = 0; ks < 2; ++ks)
          acc[1][fm][fn] = __builtin_amdgcn_mfma_f32_16x16x32_bf16(
              af[fm][ks], bfr[fn][ks], acc[1][fm][fn], 0, 0, 0);
    __builtin_amdgcn_s_setprio(0);
    asm volatile("s_barrier" ::: "memory");
  }

  // epilogue
#pragma unroll
  for (int h = 0; h < 2; ++h)
#pragma unroll
    for (int fm = 0; fm < 4; ++fm)
#pragma unroll
      for (int fn = 0; fn < 2; ++fn)
#pragma unroll
        for (int r = 0; r < 4; ++r) {
          const int row = m0 + wm2 * 64 + fm * 16 + g * 4 + r;
          const int col = n0 + h * 128 + wn2 * 32 + fn * 16 + l15;
          if (BF16OUT)
            ((unsigned short*)Cout)[(size_t)row * N + col] = f2bf(acc[h][fm][fn][r]);
          else
            ((float*)Cout)[(size_t)row * N + col] = acc[h][fm][fn][r];
        }
}

// ----------------- in-place LayerNorm on q,k parts of qkv -------------------
// q gets *= q_scale * (1/sqrt(128))*log2(e) so attn uses exp2 directly.
__global__ __launch_bounds__(256) void k_ln(unsigned short* __restrict__ qkv,
                                            const float* __restrict__ qsc,
                                            const float* __restrict__ ksc) {
  __shared__ float red[8];
  const int t = threadIdx.x;
  const int w = t >> 6;
  unsigned short* base = qkv + (size_t)blockIdx.x * 6144;
#pragma unroll
  for (int part = 0; part < 2; ++part) {
    unsigned short* p = base + part * 2048 + t * 8;
    s16x8 v = *(const s16x8*)p;
    float f[8], s = 0.f, q = 0.f;
#pragma unroll
    for (int j = 0; j < 8; j++) { f[j] = bf2f((unsigned short)v[j]); s += f[j]; q += f[j] * f[j]; }
#pragma unroll
    for (int m = 1; m < 64; m <<= 1) { s += __shfl_xor(s, m); q += __shfl_xor(q, m); }
    __syncthreads();
    if ((t & 63) == 0) { red[w] = s; red[4 + w] = q; }
    __syncthreads();
    s = red[0] + red[1] + red[2] + red[3];
    q = red[4] + red[5] + red[6] + red[7];
    float mean = s * (1.f / 2048.f);
    float var = q * (1.f / 2048.f) - mean * mean;
    float inv = rsqrtf(var + 1e-6f);
    const float* sc = part ? ksc : qsc;
    float extra = part ? 1.0f : 0.12751743f;  // (1/sqrt(128))*log2(e)
    s16x8 o;
#pragma unroll
    for (int j = 0; j < 8; j++) o[j] = (short)f2bf((f[j] - mean) * inv * (sc[t * 8 + j] * extra));
    *(s16x8*)p = o;
  }
}

// ------ v part of qkv (bf16) -> v_t [b][h][d][2048], PV-fragment order ------
__global__ __launch_bounds__(256) void k_vT(const unsigned short* __restrict__ qkv,
                                            unsigned short* __restrict__ vt) {
  __shared__ unsigned short tl[64][136];
  const int bh = blockIdx.y;
  const int b = bh >> 4, h = bh & 15;
  const int s0 = blockIdx.x * 64;
  const int t = threadIdx.x;
#pragma unroll
  for (int it = 0; it < 4; ++it) {
    int flat = it * 256 + t;
    int r = flat >> 4, c = flat & 15;
    s16x8 v = *(const s16x8*)(qkv + (size_t)(b * 2048 + s0 + r) * 6144 + 4096 + h * 128 + c * 8);
    *((s16x8*)&tl[r][c * 8]) = v;
  }
  __syncthreads();
#pragma unroll
  for (int it = 0; it < 4; ++it) {
    int flat = it * 256 + t;
    int d = flat >> 3, cs = flat & 7;
    s16x8 o;
#pragma unroll
    for (int e = 0; e < 8; e++) {
      int key = (cs >> 2) * 32 + (e >> 2) * 16 + (cs & 3) * 4 + (e & 3);
      o[e] = (short)tl[key][d];
    }
    *(s16x8*)(vt + (size_t)(bh * 128 + d) * 2048 + s0 + cs * 8) = o;
  }
}

// --------------------------- causal flash attention -------------------------
__global__ __launch_bounds__(256) void k_attn(const unsigned short* __restrict__ qkv,
                                              const unsigned short* __restrict__ vt,
                                              unsigned short* __restrict__ ctx) {
  __shared__ unsigned short sK[2][64 * 128];
  __shared__ unsigned short sV[2][128 * 64];
  const int t = threadIdx.x;
  const int w = t >> 6, lane = t & 63, g = lane >> 4, l15 = lane & 15;
  const int pair = blockIdx.x, h = blockIdx.y, b = blockIdx.z;
  const int qt0 = 31 - pair, qt1 = pair;
  const int n0 = qt0 + 1;
  const int NT = 33;
  const unsigned short* kbase = qkv + (size_t)(b * 2048) * 6144 + 2048 + h * 128;
  const unsigned short* vbase = vt + (size_t)((b * 16 + h) * 128) * 2048;

  auto issue_kv = [&](int k0, int bufi) {
#pragma unroll
    for (int it2 = 0; it2 < 4; ++it2) {
      int flat = it2 * 256 + t;
      int r = flat >> 4, c = flat & 15;
      gload_lds16(kbase + (size_t)(k0 + r) * 6144 + ((c ^ (r & 15)) * 8),
                  (unsigned short*)&sK[bufi][(it2 * 256 + w * 64) * 8]);
    }
#pragma unroll
    for (int it2 = 0; it2 < 4; ++it2) {
      int flat = it2 * 256 + t;
      int d = flat >> 3, z = flat & 7;
      gload_lds16(vbase + (size_t)d * 2048 + k0 + ((z ^ (d & 7)) * 8),
                  (unsigned short*)&sV[bufi][(it2 * 256 + w * 64) * 8]);
    }
  };

  s16x8 bq[4];
  auto load_q = [&](int q0) {
#pragma unroll
    for (int ks = 0; ks < 4; ++ks)
      bq[ks] = *(const s16x8*)(qkv + (size_t)(b * 2048 + q0 + w * 16 + l15) * 6144 +
                               h * 128 + (ks * 4 + g) * 8);
  };

  f32x4 o[8];
  float mrun, lrun;
  auto reset_state = [&]() {
#pragma unroll
    for (int nd = 0; nd < 8; ++nd) o[nd] = (f32x4){0.f, 0.f, 0.f, 0.f};
    mrun = -INFINITY; lrun = 0.f;
  };
  auto write_o = [&](int q0) {
    float ivr[4];
#pragma unroll
    for (int r = 0; r < 4; ++r) ivr[r] = 1.0f / __shfl(lrun, 4 * g + r);
#pragma unroll
    for (int nd = 0; nd < 8; ++nd) {
      const int col = h * 128 + nd * 16 + l15;
#pragma unroll
      for (int r = 0; r < 4; ++r) {
        const int row = b * 2048 + q0 + w * 16 + 4 * g + r;
        ctx[(size_t)row * 2048 + col] = f2bf(o[nd][r] * ivr[r]);
      }
    }
  };

  reset_state();
  load_q(qt0 * 64);
  issue_kv(0, 0);
  int cur = 0;

  for (int it = 0; it < NT; ++it) {
    const int seg = (it < n0) ? 0 : 1;
    const int qt = seg ? qt1 : qt0;
    const int kt = seg ? it - n0 : it;

    if (it + 1 < NT) {
      const int kn = (it + 1 < n0) ? it + 1 : it + 1 - n0;
      issue_kv(kn * 64, cur ^ 1);
      asm volatile("s_waitcnt vmcnt(8)" ::: "memory");
    } else {
      asm volatile("s_waitcnt vmcnt(0)" ::: "memory");
    }
    __builtin_amdgcn_sched_barrier(0);
    __builtin_amdgcn_s_barrier();

    if (seg == 1 && kt == 0) {
      write_o(qt0 * 64);
      reset_state();
      load_q(qt1 * 64);
    }

    const unsigned short* sKc = &sK[cur][0];
    const unsigned short* sVc = &sV[cur][0];

    f32x4 st[4];
#pragma unroll
    for (int mi = 0; mi < 4; ++mi) st[mi] = (f32x4){0.f, 0.f, 0.f, 0.f};
#pragma unroll
    for (int mi = 0; mi < 4; ++mi) {
#pragma unroll
      for (int ks = 0; ks < 4; ++ks) {
        s16x8 ak = *(const s16x8*)&sKc[(mi * 16 + l15) * 128 + (((ks * 4 + g) ^ l15) * 8)];
        st[mi] = __builtin_amdgcn_mfma_f32_16x16x32_bf16(ak, bq[ks], st[mi], 0, 0, 0);
      }
    }

    if (kt == qt) {
      const int qloc = w * 16 + l15;
#pragma unroll
      for (int mi = 0; mi < 4; ++mi)
#pragma unroll
        for (int r = 0; r < 4; ++r)
          if (mi * 16 + 4 * g + r > qloc) st[mi][r] = -INFINITY;
    }

    float mt = -INFINITY;
#pragma unroll
    for (int mi = 0; mi < 4; ++mi)
#pragma unroll
      for (int r = 0; r < 4; ++r) mt = fmaxf(mt, st[mi][r]);
    mt = fmaxf(mt, __shfl_xor(mt, 16));
    mt = fmaxf(mt, __shfl_xor(mt, 32));

    if (!__all(mt <= mrun + 8.f)) {
      const float mnew = fmaxf(mrun, mt);
      const float alpha = exp2f(mrun - mnew);
      lrun *= alpha;
      float ar[4];
#pragma unroll
      for (int r = 0; r < 4; ++r) ar[r] = __shfl(alpha, 4 * g + r);
#pragma unroll
      for (int nd = 0; nd < 8; ++nd)
#pragma unroll
        for (int r = 0; r < 4; ++r) o[nd][r] *= ar[r];
      mrun = mnew;
    }

    float ls = 0.f;
#pragma unroll
    for (int mi = 0; mi < 4; ++mi)
#pragma unroll
      for (int r = 0; r < 4; ++r) {
        float pp = exp2f(st[mi][r] - mrun);
        st[mi][r] = pp;
        ls += pp;
      }
    ls += __shfl_xor(ls, 16);
    ls += __shfl_xor(ls, 32);
    lrun += ls;

    s16x8 pa01, pa23;
#pragma unroll
    for (int j = 0; j < 8; ++j) {
      pa01[j] = (short)f2bf(st[j >> 2][j & 3]);
      pa23[j] = (short)f2bf(st[2 + (j >> 2)][j & 3]);
    }

#pragma unroll
    for (int nd = 0; nd < 8; ++nd) {
      const int d = nd * 16 + l15;
      const int zs = d & 7;
      s16x8 bv0 = *(const s16x8*)&sVc[d * 64 + ((g ^ zs) * 8)];
      s16x8 bv1 = *(const s16x8*)&sVc[d * 64 + (((4 + g) ^ zs) * 8)];
      o[nd] = __builtin_amdgcn_mfma_f32_16x16x32_bf16(pa01, bv0, o[nd], 0, 0, 0);
      o[nd] = __builtin_amdgcn_mfma_f32_16x16x32_bf16(pa23, bv1, o[nd], 0, 0, 0);
    }

    __builtin_amdgcn_sched_barrier(0);
    __builtin_amdgcn_s_barrier();
    cur ^= 1;
  }
  write_o(qt1 * 64);
}

// ---------------------------------------------------------------------------
extern "C" void kernel_launch(void* const* d_in, const int* in_sizes, int n_in,
                              void* d_out, int out_size, void* d_ws, size_t ws_size,
                              hipStream_t stream) {
  (void)in_sizes; (void)n_in; (void)out_size; (void)ws_size;
  const float* x    = (const float*)d_in[0];
  const float* Wqkv = (const float*)d_in[1];
  const float* qsc  = (const float*)d_in[2];
  const float* ksc  = (const float*)d_in[3];
  const float* outW = (const float*)d_in[4];

  char* ws = (char*)d_ws;
  unsigned short* xb  = (unsigned short*)(ws);              // 16.8MB (reused as ctx)
  unsigned short* wT  = (unsigned short*)(ws + 16777216);   // 25.2MB  Wqkv^T bf16
  unsigned short* owT = (unsigned short*)(ws + 41943040);   // 8.4MB   out_W^T bf16
  unsigned short* qkv = (unsigned short*)(ws + 50331648);   // 50.3MB  qkv bf16 (LN in place)
  unsigned short* vt  = (unsigned short*)(ws + 100663296);  // 16.8MB  v^T per head
  unsigned short* ctx = xb;                                 // x dead after QKV GEMM

  k_cvt4<<<8192, 256, 0, stream>>>((const float4*)x, (s16x4*)xb, 2097152);
  k_twT<<<dim3(192, 64), 256, 0, stream>>>(Wqkv, wT, 2048, 6144);
  k_twT<<<dim3(64, 64), 256, 0, stream>>>(outW, owT, 2048, 2048);
  k_g8p<1><<<768, 512, 0, stream>>>(xb, wT, qkv, 6144, 2048, 24);
  k_ln<<<4096, 256, 0, stream>>>(qkv, qsc, ksc);
  k_vT<<<dim3(32, 32), 256, 0, stream>>>(qkv, vt);
  k_attn<<<dim3(16, 16, 2), 256, 0, stream>>>(qkv, vt, ctx);
  k_g8p<0><<<256, 512, 0, stream>>>(ctx, owT, d_out, 2048, 2048, 8);
}